// Round 6
// baseline (521.209 us; speedup 1.0000x reference)
//
#include <hip/hip_runtime.h>
#include <hip/hip_fp16.h>

#define NN 50000
#define FF 128
#define EE 800000
#define ALPHA 0.2f
#define ESHIFT 4.0f   // global shift inside exp: softmax-invariant, keeps ex in half range

#define NBINS 196     // coarse bin = row >> 8
#define CAPB 5120     // entries per bin (avg 4082, sigma ~64)
#define EPB 2048      // edges per k_bin block (256 thr x 8)
#define NWIN 784      // 4 windows/bin, 64 rows each
#define WCAP 1600     // entry slots per window (avg 1024; pad-to-4 adds <=192)
#define NSL 8         // feature slices
#define SLW 16        // halves per slice; slab = NN*SLW*2B = 1.6 MB (fits 4MB/XCD L2)
#define BPS 2048      // hop blocks per slice (power of 2; blockIdx>>11 = slice)
#define WPS (BPS * 4) // waves per slice

// union-punning ONLY (strict-aliasing-safe, the R1-proven idiom).
// reinterpret_cast punning of stack locals was R3-R5's correctness bug.
union H4 { uint2 u; __half2 h[2]; };
union H2 { unsigned u; int i; __half2 h; };

// w1[k] = sum_j W[k,j]*a[j],  w2[k] = sum_j W[k,j]*a[F+j]
__global__ void k_w(const float* __restrict__ W, const float* __restrict__ a,
                    float* __restrict__ w12) {
    int k = threadIdx.x;  // 0..127
    float s1 = 0.f, s2 = 0.f;
    const float* wr = W + k * FF;
    for (int j = 0; j < FF; ++j) {
        float w = wr[j];
        s1 += w * a[j];
        s2 += w * a[FF + j];
    }
    w12[k] = s1;
    w12[FF + k] = s2;
}

// f1[n] = x[n,:]·w1, f2[n] = x[n,:]·w2 ; also x row -> half, SLAB-MAJOR [NSL][N][SLW]
__global__ void k_f(const float* __restrict__ x, const float* __restrict__ w12,
                    float* __restrict__ f1, float* __restrict__ f2,
                    __half* __restrict__ xh) {
    int gid = blockIdx.x * blockDim.x + threadIdx.x;
    int node = gid >> 6;
    int lane = threadIdx.x & 63;
    if (node >= NN) return;
    float2 xv = ((const float2*)(x + (size_t)node * FF))[lane];
    int slab = lane >> 3, p = lane & 7;  // features 2*lane,2*lane+1 -> slab f>>4
    ((__half2*)(xh + ((size_t)slab * NN + node) * SLW))[p] = __float22half2_rn(xv);
    float2 w1 = ((const float2*)w12)[lane];
    float2 w2 = ((const float2*)(w12 + FF))[lane];
    float s1 = xv.x * w1.x + xv.y * w1.y;
    float s2 = xv.x * w2.x + xv.y * w2.y;
#pragma unroll
    for (int o = 32; o > 0; o >>= 1) {
        s1 += __shfl_down(s1, o);
        s2 += __shfl_down(s2, o);
    }
    if (lane == 0) { f1[node] = s1; f2[node] = s2; }
}

// E1: bin edges by row>>8. LDS histogram -> one global atomic per bin per block.
// entry = ( (r<<16)|c , half2(ex, ew*ex) )  8 bytes.
__global__ void k_bin(const int* __restrict__ rows, const int* __restrict__ cols,
                      const float* __restrict__ ew, const float* __restrict__ f1,
                      const float* __restrict__ f2, int* __restrict__ bin_fill,
                      int2* __restrict__ binbuf) {
    __shared__ int cnt[NBINS];
    __shared__ int gbase[NBINS];
    int tid = threadIdx.x;
    if (tid < NBINS) cnt[tid] = 0;
    __syncthreads();
    int e0 = blockIdx.x * EPB;
    int rk[8], bn[8], rc[8], pay[8];
    bool vl[8];
#pragma unroll
    for (int k = 0; k < 8; ++k) {
        int e = e0 + k * 256 + tid;
        vl[k] = e < EE;
        if (vl[k]) {
            int r = rows[e], c = cols[e];
            float v = f1[r] + f2[c];
            v = v > 0.f ? v : ALPHA * v;
            float ex = __expf(v - ESHIFT);
            H2 p;
            p.h = __floats2half2_rn(ex, ew[e] * ex);
            pay[k] = p.i;
            rc[k] = (r << 16) | c;
            bn[k] = r >> 8;
            rk[k] = atomicAdd(&cnt[bn[k]], 1);
        }
    }
    __syncthreads();
    if (tid < NBINS) {
        int c0 = cnt[tid];
        gbase[tid] = c0 ? atomicAdd(&bin_fill[tid], c0) : 0;
    }
    __syncthreads();
#pragma unroll
    for (int k = 0; k < 8; ++k) {
        if (vl[k]) {
            int pos = gbase[bn[k]] + rk[k];
            if (pos < CAPB) binbuf[(size_t)bn[k] * CAPB + pos] = make_int2(rc[k], pay[k]);
        }
    }
}

// E2: one block per 64-row window: histogram -> scan (pad deg to x4) -> cursor
// scatter to segmented CSR. Epilogue also computes rs[r] = 0.5*sum(ew*ex)/sum(ex)
// so the hops never need the sw accumulator. rowinfo[r] = (beg, padded_deg).
__global__ void k_csr(const int* __restrict__ bin_fill, const int2* __restrict__ binbuf,
                      int2* __restrict__ csr, int2* __restrict__ rowinfo,
                      float* __restrict__ rs) {
    __shared__ int lfill[64];
    __shared__ int pbase[65];
    __shared__ int cursor[64];
    int tid = threadIdx.x;
    int w = blockIdx.x;
    int bin = w >> 2, q = w & 3;
    int cnt = bin_fill[bin];
    if (cnt > CAPB) cnt = CAPB;
    if (tid < 64) lfill[tid] = 0;
    __syncthreads();
    const int2* bb = binbuf + (size_t)bin * CAPB;
    for (int i = tid; i < cnt; i += 256) {
        int rl = (bb[i].x >> 16) & 0xFF;
        if ((rl >> 6) == q) atomicAdd(&lfill[rl & 63], 1);
    }
    __syncthreads();
    if (tid < 64) {
        int pc = (lfill[tid] + 3) & ~3;
        int s = pc;
#pragma unroll
        for (int o = 1; o < 64; o <<= 1) {
            int t = __shfl_up(s, o);
            if (tid >= o) s += t;
        }
        pbase[tid + 1] = s;
        if (tid == 0) pbase[0] = 0;
    }
    __syncthreads();
    int wbase = w * WCAP;
    if (tid < 64) cursor[tid] = wbase + pbase[tid];
    __syncthreads();
    for (int i = tid; i < cnt; i += 256) {
        int2 e = bb[i];
        int rl = (e.x >> 16) & 0xFF;
        if ((rl >> 6) == q) {
            int p = atomicAdd(&cursor[rl & 63], 1);
            csr[p] = make_int2(e.x & 0xFFFF, e.y);
        }
    }
    __syncthreads();
    if (tid < 64) {
        int r = (bin << 8) + (q << 6) + tid;
        if (r < NN) {
            int beg = wbase + pbase[tid];
            int dreal = lfill[tid];
            int dpad = (dreal + 3) & ~3;
            float se = 0.f, sw = 0.f;
            for (int i = 0; i < dreal; ++i) {
                H2 pu;
                pu.i = csr[beg + i].y;
                float2 f = __half22float2(pu.h);
                se += f.x;
                sw += f.y;
            }
            rs[r] = se > 0.f ? 0.5f * sw / se : 0.f;
            for (int t = dreal; t < dpad; ++t) csr[beg + t] = make_int2(0, 0);
            rowinfo[r] = make_int2(beg, dpad);
        }
    }
}

// per-row output for one 16-feature slice (lanes 0..3 hold fc 0..3)
__device__ __forceinline__ void emit_row(
    int step, int r, int sl, int fc, float a0, float a1, float a2, float a3, float se,
    __half* __restrict__ uout_s, __half* __restrict__ S_s, const float* __restrict__ rs,
    const float* __restrict__ x, float* __restrict__ out,
    float w0, float w1c, float w2c, float coe0)
{
    float inv = se > 0.f ? 1.f / se : 0.f;
    a0 *= inv; a1 *= inv; a2 *= inv; a3 *= inv;
    size_t pos = (size_t)r * SLW;
    if (step == 0) {
        H4 o1;
        o1.h[0] = __floats2half2_rn(a0, a1);
        o1.h[1] = __floats2half2_rn(a2, a3);
        ((uint2*)(uout_s + pos))[fc] = o1.u;
        H4 o2;
        o2.h[0] = __floats2half2_rn(w0 * a0, w0 * a1);
        o2.h[1] = __floats2half2_rn(w0 * a2, w0 * a3);
        ((uint2*)(S_s + pos))[fc] = o2.u;
    } else if (step == 1) {
        H4 o1;
        o1.h[0] = __floats2half2_rn(a0, a1);
        o1.h[1] = __floats2half2_rn(a2, a3);
        ((uint2*)(uout_s + pos))[fc] = o1.u;
        H4 sv;
        sv.u = ((const uint2*)(S_s + pos))[fc];
        float2 s0 = __half22float2(sv.h[0]);
        float2 s1 = __half22float2(sv.h[1]);
        H4 sp;
        sp.h[0] = __floats2half2_rn(s0.x + w1c * a0, s0.y + w1c * a1);
        sp.h[1] = __floats2half2_rn(s1.x + w1c * a2, s1.y + w1c * a3);
        ((uint2*)(S_s + pos))[fc] = sp.u;
    } else {
        float rsv = rs[r];
        float k1 = 1.f - rsv, k2 = coe0 * rsv;
        H4 sv;
        sv.u = ((const uint2*)(S_s + pos))[fc];
        float2 s0 = __half22float2(sv.h[0]);
        float2 s1 = __half22float2(sv.h[1]);
        float4 xv = ((const float4*)(x + (size_t)r * FF + sl * SLW))[fc];
        float4 res;
        res.x = k1 * (s0.x + w2c * a0) - k2 * xv.x;
        res.y = k1 * (s0.y + w2c * a1) - k2 * xv.y;
        res.z = k1 * (s1.x + w2c * a2) - k2 * xv.z;
        res.w = k1 * (s1.y + w2c * a3) - k2 * xv.w;
        ((float4*)(out + (size_t)r * FF + sl * SLW))[fc] = res;
    }
}

// one hop, SLICED: block -> (slice = blockIdx>>11, 2048 blocks/slice). Slices are
// independent within a hop (disjoint u/S slabs, shared read-only CSR) so no
// ordering is required for correctness; in-order dispatch keeps the current
// 1.6 MB uin slab L2-resident => gathers become L2 hits instead of L3 random.
// Wave layout: slot = lane>>2 (16 edge slots), fc = lane&3 (4 halves each).
// CSR entries nontemporal (streamed 8x/hop) so they don't evict the slab.
__global__ __launch_bounds__(256) void k_hop(
    const float* __restrict__ x, const __half* __restrict__ uin,
    __half* __restrict__ uout, const int2* __restrict__ rowinfo,
    const int2* __restrict__ csr, const float* __restrict__ temp,
    const float* __restrict__ rs, __half* __restrict__ S,
    float* __restrict__ out, int step)
{
    int wave = threadIdx.x >> 6, lane = threadIdx.x & 63;
    int sl = blockIdx.x >> 11;
    int wid = ((blockIdx.x & (BPS - 1)) << 2) + wave;
    int slot = lane >> 2, fc = lane & 3;
    const __half* uin_s = uin + (size_t)sl * NN * SLW;
    __half* uout_s = uout + (size_t)sl * NN * SLW;
    __half* S_s = S + (size_t)sl * NN * SLW;
    float c2 = 1.f / (1.f + __expf(-temp[2]));
    float coe0 = 1.f / (1.f + __expf(-temp[0]));
    float w0 = c2 * c2, w1c = c2 * (1.f - c2), w2c = 1.f - c2;
    for (int r0 = wid; r0 < NN; r0 += WPS * 2) {
        int rr1 = r0 + WPS;
        int2 ri0 = rowinfo[r0];
        int beg0 = ri0.x, d0 = ri0.y;
        int beg1 = 0, d1 = 0;
        if (rr1 < NN) { int2 ri1 = rowinfo[rr1]; beg1 = ri1.x; d1 = ri1.y; }
        const unsigned long long* bk0 = (const unsigned long long*)(csr + beg0);
        const unsigned long long* bk1 = (const unsigned long long*)(csr + beg1);
        float a00 = 0.f, a01 = 0.f, a02 = 0.f, a03 = 0.f, se0 = 0.f;
        float a10 = 0.f, a11 = 0.f, a12 = 0.f, a13 = 0.f, se1 = 0.f;
        int dmax = d0 > d1 ? d0 : d1;
        for (int j = slot; j < dmax; j += 16) {
            unsigned long long b0 = 0, b1 = 0;
            if (j < d0) b0 = __builtin_nontemporal_load(bk0 + j);
            if (j < d1) b1 = __builtin_nontemporal_load(bk1 + j);
            H4 v0, v1;
            v0.u = make_uint2(0, 0);
            v1.u = make_uint2(0, 0);
            if (j < d0) v0.u = ((const uint2*)(uin_s + (size_t)(b0 & 0xFFFF) * SLW))[fc];
            if (j < d1) v1.u = ((const uint2*)(uin_s + (size_t)(b1 & 0xFFFF) * SLW))[fc];
            if (j < d0) {
                H2 p0;
                p0.u = (unsigned)(b0 >> 32);
                float2 ee = __half22float2(p0.h);
                float ex = ee.x;
                float2 g0 = __half22float2(v0.h[0]);
                float2 g1 = __half22float2(v0.h[1]);
                se0 += ex;
                a00 += ex * g0.x; a01 += ex * g0.y; a02 += ex * g1.x; a03 += ex * g1.y;
            }
            if (j < d1) {
                H2 p1;
                p1.u = (unsigned)(b1 >> 32);
                float2 ee = __half22float2(p1.h);
                float ex = ee.x;
                float2 g0 = __half22float2(v1.h[0]);
                float2 g1 = __half22float2(v1.h[1]);
                se1 += ex;
                a10 += ex * g0.x; a11 += ex * g0.y; a12 += ex * g1.x; a13 += ex * g1.y;
            }
        }
#pragma unroll
        for (int o = 4; o < 64; o <<= 1) {
            a00 += __shfl_xor(a00, o); a01 += __shfl_xor(a01, o);
            a02 += __shfl_xor(a02, o); a03 += __shfl_xor(a03, o);
            a10 += __shfl_xor(a10, o); a11 += __shfl_xor(a11, o);
            a12 += __shfl_xor(a12, o); a13 += __shfl_xor(a13, o);
            se0 += __shfl_xor(se0, o); se1 += __shfl_xor(se1, o);
        }
        if (slot == 0) {
            emit_row(step, r0, sl, fc, a00, a01, a02, a03, se0,
                     uout_s, S_s, rs, x, out, w0, w1c, w2c, coe0);
            if (rr1 < NN)
                emit_row(step, rr1, sl, fc, a10, a11, a12, a13, se1,
                         uout_s, S_s, rs, x, out, w0, w1c, w2c, coe0);
        }
    }
}

extern "C" void kernel_launch(void* const* d_in, const int* in_sizes, int n_in,
                              void* d_out, int out_size, void* d_ws, size_t ws_size,
                              hipStream_t stream) {
    const float* x = (const float*)d_in[0];
    // d_in[1] = h0 : unused by the reference
    const int* eidx = (const int*)d_in[2];
    const int* rows = eidx;
    const int* cols = eidx + EE;
    const float* ew = (const float*)d_in[3];
    const float* W = (const float*)d_in[4];
    const float* a = (const float*)d_in[5];
    const float* temp = (const float*)d_in[6];
    float* out = (float*)d_out;

    float* ws = (float*)d_ws;
    int* bin_fill = (int*)ws;                 // 256 slots
    float* w12 = ws + 256;                    // 256
    float* f1 = ws + 512;                     // N
    float* f2 = f1 + NN;                      // N
    float* rs = f2 + NN;                      // N
    int2* rowinfo = (int2*)(rs + NN);         // N int2
    int2* csr = rowinfo + NN;                           // NWIN*WCAP*8B = 10.04 MB
    __half* xh = (__half*)(csr + (size_t)NWIN * WCAP);  // [NSL][N][SLW] = 12.8 MB
    __half* uh0 = xh + (size_t)NSL * NN * SLW;          // 12.8 MB
    __half* Sb = uh0 + (size_t)NSL * NN * SLW;          // 12.8 MB
    int2* binbuf = (int2*)Sb;  // 8.03 MB, dead before Sb's first write (hop 0)
    __half* uh1 = xh;          // xh dead after hop 0 reads it — alias

    (void)hipMemsetAsync(bin_fill, 0, NBINS * sizeof(int), stream);

    k_w<<<1, 128, 0, stream>>>(W, a, w12);
    k_f<<<(NN + 3) / 4, 256, 0, stream>>>(x, w12, f1, f2, xh);
    k_bin<<<(EE + EPB - 1) / EPB, 256, 0, stream>>>(rows, cols, ew, f1, f2, bin_fill, binbuf);
    k_csr<<<NWIN, 256, 0, stream>>>(bin_fill, binbuf, csr, rowinfo, rs);
    k_hop<<<NSL * BPS, 256, 0, stream>>>(x, xh, uh0, rowinfo, csr, temp, rs, Sb, out, 0);
    k_hop<<<NSL * BPS, 256, 0, stream>>>(x, uh0, uh1, rowinfo, csr, temp, rs, Sb, out, 1);
    k_hop<<<NSL * BPS, 256, 0, stream>>>(x, uh1, uh0, rowinfo, csr, temp, rs, Sb, out, 2);
}

// Round 7
// 280.206 us; speedup vs baseline: 1.8601x; 1.8601x over previous
//
#include <hip/hip_runtime.h>
#include <hip/hip_fp16.h>

#define NN 50000
#define HALFN 25000   // NN/2, rows per hop-wave pair
#define FF 128
#define EE 800000
#define ALPHA 0.2f
#define ESHIFT 4.0f   // global shift inside exp: softmax-invariant, keeps ex in half range

#define NBINS 196     // coarse bin = row >> 8
#define CAPB 5120     // entries per bin (avg 4082, sigma ~64)
#define EPB 2048      // edges per k_bin block (256 thr x 8)
#define NWIN 784      // 4 windows/bin, 64 rows each
#define WCAP 1600     // entry slots per window (avg 1024; pad-to-4 adds <=192)

// union-punning ONLY (strict-aliasing-safe; reinterpret_cast punning of stack
// locals was the R3-R5 correctness bug).
union H2 { unsigned u; int i; __half2 h; };
union G4 { uint4 u; __half2 h2[4]; };

// w1[k] = sum_j W[k,j]*a[j],  w2[k] = sum_j W[k,j]*a[F+j]
__global__ void k_w(const float* __restrict__ W, const float* __restrict__ a,
                    float* __restrict__ w12) {
    int k = threadIdx.x;  // 0..127
    float s1 = 0.f, s2 = 0.f;
    const float* wr = W + k * FF;
    for (int j = 0; j < FF; ++j) {
        float w = wr[j];
        s1 += w * a[j];
        s2 += w * a[FF + j];
    }
    w12[k] = s1;
    w12[FF + k] = s2;
}

// f1[n] = x[n,:]·w1, f2[n] = x[n,:]·w2 ; also convert x row -> half (xh, row-major)
__global__ void k_f(const float* __restrict__ x, const float* __restrict__ w12,
                    float* __restrict__ f1, float* __restrict__ f2,
                    __half* __restrict__ xh) {
    int gid = blockIdx.x * blockDim.x + threadIdx.x;
    int node = gid >> 6;
    int lane = threadIdx.x & 63;
    if (node >= NN) return;
    float2 xv = ((const float2*)(x + (size_t)node * FF))[lane];
    ((__half2*)(xh + (size_t)node * FF))[lane] = __float22half2_rn(xv);
    float2 w1 = ((const float2*)w12)[lane];
    float2 w2 = ((const float2*)(w12 + FF))[lane];
    float s1 = xv.x * w1.x + xv.y * w1.y;
    float s2 = xv.x * w2.x + xv.y * w2.y;
#pragma unroll
    for (int o = 32; o > 0; o >>= 1) {
        s1 += __shfl_down(s1, o);
        s2 += __shfl_down(s2, o);
    }
    if (lane == 0) { f1[node] = s1; f2[node] = s2; }
}

// E1: bin edges by row>>8. LDS histogram -> one global atomic per bin per block.
// entry = ( (r<<16)|c , half2(ex, ew*ex) )  8 bytes.
__global__ void k_bin(const int* __restrict__ rows, const int* __restrict__ cols,
                      const float* __restrict__ ew, const float* __restrict__ f1,
                      const float* __restrict__ f2, int* __restrict__ bin_fill,
                      int2* __restrict__ binbuf) {
    __shared__ int cnt[NBINS];
    __shared__ int gbase[NBINS];
    int tid = threadIdx.x;
    if (tid < NBINS) cnt[tid] = 0;
    __syncthreads();
    int e0 = blockIdx.x * EPB;
    int rk[8], bn[8], rc[8], pay[8];
    bool vl[8];
#pragma unroll
    for (int k = 0; k < 8; ++k) {
        int e = e0 + k * 256 + tid;
        vl[k] = e < EE;
        if (vl[k]) {
            int r = rows[e], c = cols[e];
            float v = f1[r] + f2[c];
            v = v > 0.f ? v : ALPHA * v;
            float ex = __expf(v - ESHIFT);
            H2 p;
            p.h = __floats2half2_rn(ex, ew[e] * ex);
            pay[k] = p.i;
            rc[k] = (r << 16) | c;
            bn[k] = r >> 8;
            rk[k] = atomicAdd(&cnt[bn[k]], 1);
        }
    }
    __syncthreads();
    if (tid < NBINS) {
        int c0 = cnt[tid];
        gbase[tid] = c0 ? atomicAdd(&bin_fill[tid], c0) : 0;
    }
    __syncthreads();
#pragma unroll
    for (int k = 0; k < 8; ++k) {
        if (vl[k]) {
            int pos = gbase[bn[k]] + rk[k];
            if (pos < CAPB) binbuf[(size_t)bn[k] * CAPB + pos] = make_int2(rc[k], pay[k]);
        }
    }
}

// E2: one block per 64-row window: histogram -> scan (pad deg to x4) -> cursor
// scatter to 8B staging CSR. Epilogue: per-row softmax sums -> rs[r] and a
// 4-byte final CSR: entry = col | (att_half << 16) with att = ex/sum(ex).
// Pads (att=0,col=0) contribute nothing. rowinfo[r] = (beg, padded_deg).
__global__ void k_csr(const int* __restrict__ bin_fill, const int2* __restrict__ binbuf,
                      int2* __restrict__ csr, unsigned* __restrict__ csr2,
                      int2* __restrict__ rowinfo, float* __restrict__ rs) {
    __shared__ int lfill[64];
    __shared__ int pbase[65];
    __shared__ int cursor[64];
    int tid = threadIdx.x;
    int w = blockIdx.x;
    int bin = w >> 2, q = w & 3;
    int cnt = bin_fill[bin];
    if (cnt > CAPB) cnt = CAPB;
    if (tid < 64) lfill[tid] = 0;
    __syncthreads();
    const int2* bb = binbuf + (size_t)bin * CAPB;
    for (int i = tid; i < cnt; i += 256) {
        int rl = (bb[i].x >> 16) & 0xFF;
        if ((rl >> 6) == q) atomicAdd(&lfill[rl & 63], 1);
    }
    __syncthreads();
    if (tid < 64) {
        int pc = (lfill[tid] + 3) & ~3;
        int s = pc;
#pragma unroll
        for (int o = 1; o < 64; o <<= 1) {
            int t = __shfl_up(s, o);
            if (tid >= o) s += t;
        }
        pbase[tid + 1] = s;
        if (tid == 0) pbase[0] = 0;
    }
    __syncthreads();
    int wbase = w * WCAP;
    if (tid < 64) cursor[tid] = wbase + pbase[tid];
    __syncthreads();
    for (int i = tid; i < cnt; i += 256) {
        int2 e = bb[i];
        int rl = (e.x >> 16) & 0xFF;
        if ((rl >> 6) == q) {
            int p = atomicAdd(&cursor[rl & 63], 1);
            csr[p] = make_int2(e.x & 0xFFFF, e.y);
        }
    }
    __syncthreads();
    if (tid < 64) {
        int r = (bin << 8) + (q << 6) + tid;
        if (r < NN) {
            int beg = wbase + pbase[tid];
            int dreal = lfill[tid];
            int dpad = (dreal + 3) & ~3;
            float se = 0.f, sw = 0.f;
            for (int i = 0; i < dreal; ++i) {
                H2 pu;
                pu.i = csr[beg + i].y;
                float2 f = __half22float2(pu.h);
                se += f.x;
                sw += f.y;
            }
            float inv = se > 0.f ? 1.f / se : 0.f;
            rs[r] = 0.5f * sw * inv;
            for (int i = 0; i < dreal; ++i) {
                int2 e = csr[beg + i];
                H2 pu;
                pu.i = e.y;
                float att = __half22float2(pu.h).x * inv;
                unsigned ab = (unsigned)__half_as_ushort(__float2half_rn(att));
                csr2[beg + i] = (unsigned)e.x | (ab << 16);
            }
            for (int i = dreal; i < dpad; ++i) csr2[beg + i] = 0u;
            rowinfo[r] = make_int2(beg, dpad);
        }
    }
}

// per-row output for one row (lanes with s==0; fl = 0..15 owns features 8*fl..8*fl+7)
__device__ __forceinline__ void emit_row(
    int step, int r, int fl, const float* ax, float se,
    __half* __restrict__ uout, __half* __restrict__ S, const float* __restrict__ rs,
    const float* __restrict__ x, float* __restrict__ out,
    float w0, float w1c, float w2c, float coe0)
{
    float inv = se > 0.f ? 1.f / se : 0.f;  // se = sum(att_half) ~ 1; fixes rounding
    float a[8];
#pragma unroll
    for (int k = 0; k < 8; ++k) a[k] = ax[k] * inv;
    if (step == 0) {
        G4 o1, o2;
#pragma unroll
        for (int t = 0; t < 4; ++t) {
            o1.h2[t] = __floats2half2_rn(a[2 * t], a[2 * t + 1]);
            o2.h2[t] = __floats2half2_rn(w0 * a[2 * t], w0 * a[2 * t + 1]);
        }
        ((uint4*)(uout + (size_t)r * FF))[fl] = o1.u;
        ((uint4*)(S + (size_t)r * FF))[fl] = o2.u;
    } else if (step == 1) {
        G4 o1, sv;
        sv.u = ((const uint4*)(S + (size_t)r * FF))[fl];
#pragma unroll
        for (int t = 0; t < 4; ++t) {
            o1.h2[t] = __floats2half2_rn(a[2 * t], a[2 * t + 1]);
            float2 svf = __half22float2(sv.h2[t]);
            sv.h2[t] = __floats2half2_rn(svf.x + w1c * a[2 * t],
                                         svf.y + w1c * a[2 * t + 1]);
        }
        ((uint4*)(uout + (size_t)r * FF))[fl] = o1.u;
        ((uint4*)(S + (size_t)r * FF))[fl] = sv.u;
    } else {
        float rsv = rs[r];
        float k1 = 1.f - rsv, k2 = coe0 * rsv;
        G4 sv;
        sv.u = ((const uint4*)(S + (size_t)r * FF))[fl];
        const float4* xr = (const float4*)(x + (size_t)r * FF);
        float4* orow = (float4*)(out + (size_t)r * FF);
        float4 xv0 = xr[2 * fl], xv1 = xr[2 * fl + 1];
        float res[8];
#pragma unroll
        for (int t = 0; t < 4; ++t) {
            float2 svf = __half22float2(sv.h2[t]);
            res[2 * t] = k1 * (svf.x + w2c * a[2 * t]);
            res[2 * t + 1] = k1 * (svf.y + w2c * a[2 * t + 1]);
        }
        orow[2 * fl] = make_float4(res[0] - k2 * xv0.x, res[1] - k2 * xv0.y,
                                   res[2] - k2 * xv0.z, res[3] - k2 * xv0.w);
        orow[2 * fl + 1] = make_float4(res[4] - k2 * xv1.x, res[5] - k2 * xv1.y,
                                       res[6] - k2 * xv1.z, res[7] - k2 * xv1.w);
    }
}

// one hop: wave handles TWO rows (r, r+25000) for 2x memory-level parallelism.
// Per row: 16 lanes/edge (fl=feature chunk, 16B), 4 edge slots (s), 16 edges/iter.
// 4B CSR entry = col | att_half<<16 (pre-normalized); zero entries skipped.
// u = sum(att*u[col]) / sum(att).  step0: uout=u, S=w0*u. step1: uout=u, S+=w1*u.
// step2: out = (1-rs)*(S + w2*u) - coe0*rs*x  (rs precomputed in k_csr).
__global__ __launch_bounds__(256) void k_hop(
    const float* __restrict__ x, const __half* __restrict__ uin,
    __half* __restrict__ uout, const int2* __restrict__ rowinfo,
    const unsigned* __restrict__ csr2, const float* __restrict__ temp,
    const float* __restrict__ rs, __half* __restrict__ S,
    float* __restrict__ out, int step)
{
    int wave = threadIdx.x >> 6;
    int lane = threadIdx.x & 63;
    int w = blockIdx.x * 4 + wave;      // 0..24999
    if (w >= HALFN) return;
    int s = lane >> 4;    // edge slot 0..3
    int fl = lane & 15;   // feature chunk (features 8*fl .. 8*fl+7)
    int r0 = w, r1 = w + HALFN;
    int2 ri0 = rowinfo[r0];
    int2 ri1 = rowinfo[r1];
    const unsigned* bk0 = csr2 + ri0.x;
    const unsigned* bk1 = csr2 + ri1.x;
    int d0 = ri0.y, d1 = ri1.y;
    float ax0[8], ax1[8];
#pragma unroll
    for (int k = 0; k < 8; ++k) { ax0[k] = 0.f; ax1[k] = 0.f; }
    float se0 = 0.f, se1 = 0.f;
    int dmax = d0 > d1 ? d0 : d1;
    for (int j = 0; j < dmax; j += 16) {
        unsigned b0[4], b1[4];
        G4 g0[4], g1[4];
#pragma unroll
        for (int g = 0; g < 4; ++g) {
            int e = j + 4 * g + s;
            b0[g] = e < d0 ? bk0[e] : 0u;
            b1[g] = e < d1 ? bk1[e] : 0u;
        }
#pragma unroll
        for (int g = 0; g < 4; ++g) {
            g0[g].u = make_uint4(0, 0, 0, 0);
            if (b0[g]) g0[g].u = ((const uint4*)(uin + (size_t)(b0[g] & 0xFFFF) * FF))[fl];
            g1[g].u = make_uint4(0, 0, 0, 0);
            if (b1[g]) g1[g].u = ((const uint4*)(uin + (size_t)(b1[g] & 0xFFFF) * FF))[fl];
        }
#pragma unroll
        for (int g = 0; g < 4; ++g) {
            H2 p0, p1;
            p0.u = b0[g] >> 16;
            p1.u = b1[g] >> 16;
            float at0 = __half22float2(p0.h).x;
            float at1 = __half22float2(p1.h).x;
            se0 += at0;
            se1 += at1;
#pragma unroll
            for (int t = 0; t < 4; ++t) {
                float2 u0 = __half22float2(g0[g].h2[t]);
                float2 u1 = __half22float2(g1[g].h2[t]);
                ax0[2 * t] += at0 * u0.x; ax0[2 * t + 1] += at0 * u0.y;
                ax1[2 * t] += at1 * u1.x; ax1[2 * t + 1] += at1 * u1.y;
            }
        }
    }
    // combine 4 edge slots: lanes l, l^16, l^32, l^48 share features, differ in edges
#pragma unroll
    for (int o = 16; o < 64; o <<= 1) {
#pragma unroll
        for (int k = 0; k < 8; ++k) {
            ax0[k] += __shfl_xor(ax0[k], o);
            ax1[k] += __shfl_xor(ax1[k], o);
        }
        se0 += __shfl_xor(se0, o);
        se1 += __shfl_xor(se1, o);
    }
    if (s == 0) {
        float c2 = 1.f / (1.f + __expf(-temp[2]));
        float coe0 = 1.f / (1.f + __expf(-temp[0]));
        float w0 = c2 * c2, w1c = c2 * (1.f - c2), w2c = 1.f - c2;
        emit_row(step, r0, fl, ax0, se0, uout, S, rs, x, out, w0, w1c, w2c, coe0);
        emit_row(step, r1, fl, ax1, se1, uout, S, rs, x, out, w0, w1c, w2c, coe0);
    }
}

extern "C" void kernel_launch(void* const* d_in, const int* in_sizes, int n_in,
                              void* d_out, int out_size, void* d_ws, size_t ws_size,
                              hipStream_t stream) {
    const float* x = (const float*)d_in[0];
    // d_in[1] = h0 : unused by the reference
    const int* eidx = (const int*)d_in[2];
    const int* rows = eidx;
    const int* cols = eidx + EE;
    const float* ew = (const float*)d_in[3];
    const float* W = (const float*)d_in[4];
    const float* a = (const float*)d_in[5];
    const float* temp = (const float*)d_in[6];
    float* out = (float*)d_out;

    float* ws = (float*)d_ws;
    int* bin_fill = (int*)ws;                 // 256 slots
    float* w12 = ws + 256;                    // 256
    float* f1 = ws + 512;                     // N
    float* f2 = f1 + NN;                      // N
    float* rs = f2 + NN;                      // N
    int2* rowinfo = (int2*)(rs + NN);         // N int2
    int2* csr = rowinfo + NN;                             // 8B staging, 10.04 MB
    unsigned* csr2 = (unsigned*)(csr + (size_t)NWIN * WCAP);  // 4B final, 5.02 MB
    __half* xh = (__half*)(csr2 + (size_t)NWIN * WCAP);   // N*F half = 12.8 MB
    __half* uh0 = xh + (size_t)NN * FF;                   // 12.8 MB
    __half* Sb = uh0 + (size_t)NN * FF;                   // 12.8 MB
    int2* binbuf = (int2*)Sb;  // 8.03 MB, dead before Sb's first write (hop 0)
    __half* uh1 = xh;          // xh dead after hop 0 reads it — alias

    (void)hipMemsetAsync(bin_fill, 0, NBINS * sizeof(int), stream);

    k_w<<<1, 128, 0, stream>>>(W, a, w12);
    k_f<<<(NN + 3) / 4, 256, 0, stream>>>(x, w12, f1, f2, xh);
    k_bin<<<(EE + EPB - 1) / EPB, 256, 0, stream>>>(rows, cols, ew, f1, f2, bin_fill, binbuf);
    k_csr<<<NWIN, 256, 0, stream>>>(bin_fill, binbuf, csr, csr2, rowinfo, rs);
    k_hop<<<HALFN / 4, 256, 0, stream>>>(x, xh, uh0, rowinfo, csr2, temp, rs, Sb, out, 0);
    k_hop<<<HALFN / 4, 256, 0, stream>>>(x, uh0, uh1, rowinfo, csr2, temp, rs, Sb, out, 1);
    k_hop<<<HALFN / 4, 256, 0, stream>>>(x, uh1, uh0, rowinfo, csr2, temp, rs, Sb, out, 2);
}

// Round 8
// 263.441 us; speedup vs baseline: 1.9785x; 1.0636x over previous
//
#include <hip/hip_runtime.h>
#include <hip/hip_fp16.h>

#define NN 50000
#define FF 128
#define EE 800000
#define ALPHA 0.2f
#define ESHIFT 4.0f   // global shift inside exp: softmax-invariant, keeps ex in half range

#define NBINS 196     // coarse bin = row >> 8 (256 rows per bin)
#define CAPB 5120     // entries per bin (avg 4082, sigma ~64)
#define EPB 2048      // edges per k_bin block (256 thr x 8)
#define BCAP 6144     // padded entry slots per bin (5120 + 768 pad + margin)

// union-punning ONLY (strict-aliasing-safe; reinterpret_cast punning of stack
// locals was the R3-R5 correctness bug).
union H2 { unsigned u; int i; __half2 h; };
union G4 { uint4 u; __half2 h2[4]; };

// w1[k] = sum_j W[k,j]*a[j],  w2[k] = sum_j W[k,j]*a[F+j].  Also zeroes bin_fill
// (replaces a separate hipMemsetAsync dispatch).
__global__ void k_w(const float* __restrict__ W, const float* __restrict__ a,
                    float* __restrict__ w12, int* __restrict__ bin_fill) {
    int k = threadIdx.x;  // 0..127
    for (int i = k; i < NBINS; i += 128) bin_fill[i] = 0;
    float s1 = 0.f, s2 = 0.f;
    const float* wr = W + k * FF;
    for (int j = 0; j < FF; ++j) {
        float w = wr[j];
        s1 += w * a[j];
        s2 += w * a[FF + j];
    }
    w12[k] = s1;
    w12[FF + k] = s2;
}

// f1[n] = x[n,:]·w1, f2[n] = x[n,:]·w2 ; also convert x row -> half (xh, row-major)
__global__ void k_f(const float* __restrict__ x, const float* __restrict__ w12,
                    float* __restrict__ f1, float* __restrict__ f2,
                    __half* __restrict__ xh) {
    int gid = blockIdx.x * blockDim.x + threadIdx.x;
    int node = gid >> 6;
    int lane = threadIdx.x & 63;
    if (node >= NN) return;
    float2 xv = ((const float2*)(x + (size_t)node * FF))[lane];
    ((__half2*)(xh + (size_t)node * FF))[lane] = __float22half2_rn(xv);
    float2 w1 = ((const float2*)w12)[lane];
    float2 w2 = ((const float2*)(w12 + FF))[lane];
    float s1 = xv.x * w1.x + xv.y * w1.y;
    float s2 = xv.x * w2.x + xv.y * w2.y;
#pragma unroll
    for (int o = 32; o > 0; o >>= 1) {
        s1 += __shfl_down(s1, o);
        s2 += __shfl_down(s2, o);
    }
    if (lane == 0) { f1[node] = s1; f2[node] = s2; }
}

// E1: bin edges by row>>8. LDS histogram -> one global atomic per bin per block.
// entry = ( (r<<16)|c , half2(ex, ew*ex) )  8 bytes.
__global__ void k_bin(const int* __restrict__ rows, const int* __restrict__ cols,
                      const float* __restrict__ ew, const float* __restrict__ f1,
                      const float* __restrict__ f2, int* __restrict__ bin_fill,
                      int2* __restrict__ binbuf) {
    __shared__ int cnt[NBINS];
    __shared__ int gbase[NBINS];
    int tid = threadIdx.x;
    if (tid < NBINS) cnt[tid] = 0;
    __syncthreads();
    int e0 = blockIdx.x * EPB;
    int rk[8], bn[8], rc[8], pay[8];
    bool vl[8];
#pragma unroll
    for (int k = 0; k < 8; ++k) {
        int e = e0 + k * 256 + tid;
        vl[k] = e < EE;
        if (vl[k]) {
            int r = rows[e], c = cols[e];
            float v = f1[r] + f2[c];
            v = v > 0.f ? v : ALPHA * v;
            float ex = __expf(v - ESHIFT);
            H2 p;
            p.h = __floats2half2_rn(ex, ew[e] * ex);
            pay[k] = p.i;
            rc[k] = (r << 16) | c;
            bn[k] = r >> 8;
            rk[k] = atomicAdd(&cnt[bn[k]], 1);
        }
    }
    __syncthreads();
    if (tid < NBINS) {
        int c0 = cnt[tid];
        gbase[tid] = c0 ? atomicAdd(&bin_fill[tid], c0) : 0;
    }
    __syncthreads();
#pragma unroll
    for (int k = 0; k < 8; ++k) {
        if (vl[k]) {
            int pos = gbase[bn[k]] + rk[k];
            if (pos < CAPB) binbuf[(size_t)bn[k] * CAPB + pos] = make_int2(rc[k], pay[k]);
        }
    }
}

// E2: one block per BIN (256 rows) — reads the bin buffer 2x total instead of the
// old window scheme's 8x (4 windows x 2 passes). histogram(256) -> wave-scan +
// cross-wave combine -> cursor scatter to 8B staging CSR -> per-row epilogue:
// rs[r] = 0.5*sum(ew*ex)/sum(ex), 4B final CSR entry = col | att_half<<16 with
// att = ex/sum(ex) (pre-normalized softmax), pads = 0. rowinfo[r]=(beg,dpad).
__global__ void k_csr(const int* __restrict__ bin_fill, const int2* __restrict__ binbuf,
                      int2* __restrict__ csr, unsigned* __restrict__ csr2,
                      int2* __restrict__ rowinfo, float* __restrict__ rs) {
    __shared__ int lfill[256];
    __shared__ int pbeg[256];
    __shared__ int cursor[256];
    __shared__ int wsum[4];
    int tid = threadIdx.x;
    int lane = tid & 63, wave = tid >> 6;
    int bin = blockIdx.x;
    int cnt = bin_fill[bin];
    if (cnt > CAPB) cnt = CAPB;
    lfill[tid] = 0;
    __syncthreads();
    const int2* bb = binbuf + (size_t)bin * CAPB;
    for (int i = tid; i < cnt; i += 256) {
        atomicAdd(&lfill[(bb[i].x >> 16) & 0xFF], 1);
    }
    __syncthreads();
    // exclusive scan of padded counts over 256 threads
    int pc = (lfill[tid] + 3) & ~3;
    int s = pc;
#pragma unroll
    for (int o = 1; o < 64; o <<= 1) {
        int t = __shfl_up(s, o);
        if (lane >= o) s += t;
    }
    if (lane == 63) wsum[wave] = s;
    __syncthreads();
    int woff = 0;
#pragma unroll
    for (int i = 0; i < 4; ++i)
        if (i < wave) woff += wsum[i];
    int binbase = bin * BCAP;
    int beg = binbase + woff + (s - pc);  // exclusive offset
    pbeg[tid] = beg;
    cursor[tid] = beg;
    __syncthreads();
    for (int i = tid; i < cnt; i += 256) {
        int2 e = bb[i];
        int rl = (e.x >> 16) & 0xFF;
        int p = atomicAdd(&cursor[rl], 1);
        csr[p] = make_int2(e.x & 0xFFFF, e.y);
    }
    __syncthreads();
    int r = (bin << 8) + tid;
    if (r < NN) {
        int b0 = pbeg[tid];
        int dreal = lfill[tid];
        int dpad = (dreal + 3) & ~3;
        float se = 0.f, sw = 0.f;
        for (int i = 0; i < dreal; ++i) {
            H2 pu;
            pu.i = csr[b0 + i].y;
            float2 f = __half22float2(pu.h);
            se += f.x;
            sw += f.y;
        }
        float inv = se > 0.f ? 1.f / se : 0.f;
        rs[r] = 0.5f * sw * inv;
        for (int i = 0; i < dreal; ++i) {
            int2 e = csr[b0 + i];
            H2 pu;
            pu.i = e.y;
            float att = __half22float2(pu.h).x * inv;
            unsigned ab = (unsigned)__half_as_ushort(__float2half_rn(att));
            csr2[b0 + i] = (unsigned)e.x | (ab << 16);
        }
        for (int i = dreal; i < dpad; ++i) csr2[b0 + i] = 0u;
        rowinfo[r] = make_int2(b0, dpad);
    }
}

// per-row output (lanes with s==0; fl = 0..15 owns features 8*fl..8*fl+7)
__device__ __forceinline__ void emit_row(
    int step, int r, int fl, const float* ax, float se,
    __half* __restrict__ uout, __half* __restrict__ S, const float* __restrict__ rs,
    const float* __restrict__ x, float* __restrict__ out,
    float w0, float w1c, float w2c, float coe0)
{
    float inv = se > 0.f ? 1.f / se : 0.f;  // se = sum(att_half) ~ 1; fixes rounding
    float a[8];
#pragma unroll
    for (int k = 0; k < 8; ++k) a[k] = ax[k] * inv;
    if (step == 0) {
        G4 o1, o2;
#pragma unroll
        for (int t = 0; t < 4; ++t) {
            o1.h2[t] = __floats2half2_rn(a[2 * t], a[2 * t + 1]);
            o2.h2[t] = __floats2half2_rn(w0 * a[2 * t], w0 * a[2 * t + 1]);
        }
        ((uint4*)(uout + (size_t)r * FF))[fl] = o1.u;
        ((uint4*)(S + (size_t)r * FF))[fl] = o2.u;
    } else if (step == 1) {
        G4 o1, sv;
        sv.u = ((const uint4*)(S + (size_t)r * FF))[fl];
#pragma unroll
        for (int t = 0; t < 4; ++t) {
            o1.h2[t] = __floats2half2_rn(a[2 * t], a[2 * t + 1]);
            float2 svf = __half22float2(sv.h2[t]);
            sv.h2[t] = __floats2half2_rn(svf.x + w1c * a[2 * t],
                                         svf.y + w1c * a[2 * t + 1]);
        }
        ((uint4*)(uout + (size_t)r * FF))[fl] = o1.u;
        ((uint4*)(S + (size_t)r * FF))[fl] = sv.u;
    } else {
        float rsv = rs[r];
        float k1 = 1.f - rsv, k2 = coe0 * rsv;
        G4 sv;
        sv.u = ((const uint4*)(S + (size_t)r * FF))[fl];
        const float4* xr = (const float4*)(x + (size_t)r * FF);
        float4* orow = (float4*)(out + (size_t)r * FF);
        float4 xv0 = xr[2 * fl], xv1 = xr[2 * fl + 1];
        float res[8];
#pragma unroll
        for (int t = 0; t < 4; ++t) {
            float2 svf = __half22float2(sv.h2[t]);
            res[2 * t] = k1 * (svf.x + w2c * a[2 * t]);
            res[2 * t + 1] = k1 * (svf.y + w2c * a[2 * t + 1]);
        }
        orow[2 * fl] = make_float4(res[0] - k2 * xv0.x, res[1] - k2 * xv0.y,
                                   res[2] - k2 * xv0.z, res[3] - k2 * xv0.w);
        orow[2 * fl + 1] = make_float4(res[4] - k2 * xv1.x, res[5] - k2 * xv1.y,
                                       res[6] - k2 * xv1.z, res[7] - k2 * xv1.w);
    }
}

// one hop: ONE row per wave (R1-proven geometry, 12500 blocks). 16 lanes/edge
// (fl = 16B feature chunk), 4 edge slots, 16 edges/iter. 4B CSR entry =
// col | att_half<<16, pre-normalized; pad/tail entries are 0 -> gather row 0
// (L2-hot) with att 0: contributes nothing, so no guards needed.
// u = sum(att*u[col]) / sum(att).  step0: uout=u, S=w0*u. step1: uout=u, S+=w1*u.
// step2: out = (1-rs)*(S + w2*u) - coe0*rs*x  (rs precomputed in k_csr).
__global__ __launch_bounds__(256) void k_hop(
    const float* __restrict__ x, const __half* __restrict__ uin,
    __half* __restrict__ uout, const int2* __restrict__ rowinfo,
    const unsigned* __restrict__ csr2, const float* __restrict__ temp,
    const float* __restrict__ rs, __half* __restrict__ S,
    float* __restrict__ out, int step)
{
    int wave = threadIdx.x >> 6;
    int lane = threadIdx.x & 63;
    int r = blockIdx.x * 4 + wave;
    if (r >= NN) return;
    int s = lane >> 4;    // edge slot 0..3
    int fl = lane & 15;   // feature chunk (features 8*fl .. 8*fl+7)
    int2 ri = rowinfo[r];
    const unsigned* bk = csr2 + ri.x;
    int d = ri.y;  // multiple of 4
    float ax[8];
#pragma unroll
    for (int k = 0; k < 8; ++k) ax[k] = 0.f;
    float se = 0.f;
    for (int j = 0; j < d; j += 16) {
        unsigned b[4];
        G4 g[4];
#pragma unroll
        for (int gi = 0; gi < 4; ++gi) {
            int e = j + 4 * gi + s;
            b[gi] = e < d ? bk[e] : 0u;
        }
#pragma unroll
        for (int gi = 0; gi < 4; ++gi)
            g[gi].u = ((const uint4*)(uin + (size_t)(b[gi] & 0xFFFF) * FF))[fl];
#pragma unroll
        for (int gi = 0; gi < 4; ++gi) {
            H2 p;
            p.u = b[gi] >> 16;
            float at = __half22float2(p.h).x;
            se += at;
#pragma unroll
            for (int t = 0; t < 4; ++t) {
                float2 uv = __half22float2(g[gi].h2[t]);
                ax[2 * t] += at * uv.x;
                ax[2 * t + 1] += at * uv.y;
            }
        }
    }
    // combine 4 edge slots: lanes l, l^16, l^32, l^48 share features, differ in edges
#pragma unroll
    for (int o = 16; o < 64; o <<= 1) {
#pragma unroll
        for (int k = 0; k < 8; ++k) ax[k] += __shfl_xor(ax[k], o);
        se += __shfl_xor(se, o);
    }
    if (s == 0) {
        float c2 = 1.f / (1.f + __expf(-temp[2]));
        float coe0 = 1.f / (1.f + __expf(-temp[0]));
        float w0 = c2 * c2, w1c = c2 * (1.f - c2), w2c = 1.f - c2;
        emit_row(step, r, fl, ax, se, uout, S, rs, x, out, w0, w1c, w2c, coe0);
    }
}

extern "C" void kernel_launch(void* const* d_in, const int* in_sizes, int n_in,
                              void* d_out, int out_size, void* d_ws, size_t ws_size,
                              hipStream_t stream) {
    const float* x = (const float*)d_in[0];
    // d_in[1] = h0 : unused by the reference
    const int* eidx = (const int*)d_in[2];
    const int* rows = eidx;
    const int* cols = eidx + EE;
    const float* ew = (const float*)d_in[3];
    const float* W = (const float*)d_in[4];
    const float* a = (const float*)d_in[5];
    const float* temp = (const float*)d_in[6];
    float* out = (float*)d_out;

    float* ws = (float*)d_ws;
    int* bin_fill = (int*)ws;                 // 256 slots
    float* w12 = ws + 256;                    // 256
    float* f1 = ws + 512;                     // N
    float* f2 = f1 + NN;                      // N
    float* rs = f2 + NN;                      // N
    int2* rowinfo = (int2*)(rs + NN);         // N int2
    int2* csr = rowinfo + NN;                             // 8B staging, 196*6144*8B = 9.6 MB
    unsigned* csr2 = (unsigned*)(csr + (size_t)NBINS * BCAP);  // 4B final, 4.8 MB
    __half* xh = (__half*)(csr2 + (size_t)NBINS * BCAP);  // N*F half = 12.8 MB
    __half* uh0 = xh + (size_t)NN * FF;                   // 12.8 MB
    __half* Sb = uh0 + (size_t)NN * FF;                   // 12.8 MB
    int2* binbuf = (int2*)Sb;  // 8.03 MB, dead before Sb's first write (hop 0)
    __half* uh1 = xh;          // xh dead after hop 0 reads it — alias

    k_w<<<1, 128, 0, stream>>>(W, a, w12, bin_fill);
    k_f<<<(NN + 3) / 4, 256, 0, stream>>>(x, w12, f1, f2, xh);
    k_bin<<<(EE + EPB - 1) / EPB, 256, 0, stream>>>(rows, cols, ew, f1, f2, bin_fill, binbuf);
    k_csr<<<NBINS, 256, 0, stream>>>(bin_fill, binbuf, csr, csr2, rowinfo, rs);
    k_hop<<<(NN + 3) / 4, 256, 0, stream>>>(x, xh, uh0, rowinfo, csr2, temp, rs, Sb, out, 0);
    k_hop<<<(NN + 3) / 4, 256, 0, stream>>>(x, uh0, uh1, rowinfo, csr2, temp, rs, Sb, out, 1);
    k_hop<<<(NN + 3) / 4, 256, 0, stream>>>(x, uh1, uh0, rowinfo, csr2, temp, rs, Sb, out, 2);
}